// Round 12
// baseline (389.807 us; speedup 1.0000x reference)
//
#include <hip/hip_runtime.h>
#include <math.h>

typedef unsigned int uint;
typedef unsigned short ushort;
typedef unsigned char uchar;
typedef __attribute__((ext_vector_type(2))) float v2f;

#define S1 4.0f
#define S2 16.0f

template <bool HI>
__device__ inline v2f fp8x2f(uint u) {
    return __builtin_amdgcn_cvt_pk_f32_fp8((int)u, HI);
}

// ---- GEMM1 + fused edge histogram (8 edges/thread, 64B-padded counters) ----
__global__ __launch_bounds__(256) void k_gemm1(const float* __restrict__ x,
                                               const float* __restrict__ W1,
                                               const float* __restrict__ as1,
                                               const float* __restrict__ ad1,
                                               uchar* __restrict__ h1f8,
                                               float* __restrict__ al1s,
                                               float* __restrict__ al1d,
                                               const int* __restrict__ dst,
                                               int* __restrict__ deg,   // stride-16 ints (1 counter / 64B line)
                                               int* __restrict__ rank,
                                               int E, int N) {
    __shared__ float sB[128 * 64];
    __shared__ float sA[64 * 68];
    const int t = threadIdx.x;
    const int n0 = blockIdx.x * 64;

    // fused histogram: 8 atomic returns in flight per thread (first ~782 blocks)
    int ebase = (blockIdx.x * 256 + t) * 8;
    int ra0 = 0, ra1 = 0, ra2 = 0, ra3 = 0, ra4 = 0, ra5 = 0, ra6 = 0, ra7 = 0;
    bool efull = (ebase + 8 <= E);
    if (efull) {
        int4 d0 = *(const int4*)&dst[ebase];
        int4 d1 = *(const int4*)&dst[ebase + 4];
        ra0 = atomicAdd(&deg[d0.x * 16], 1);
        ra1 = atomicAdd(&deg[d0.y * 16], 1);
        ra2 = atomicAdd(&deg[d0.z * 16], 1);
        ra3 = atomicAdd(&deg[d0.w * 16], 1);
        ra4 = atomicAdd(&deg[d1.x * 16], 1);
        ra5 = atomicAdd(&deg[d1.y * 16], 1);
        ra6 = atomicAdd(&deg[d1.z * 16], 1);
        ra7 = atomicAdd(&deg[d1.w * 16], 1);
    } else if (ebase < E) {
        for (int e = ebase; e < E; ++e) rank[e] = atomicAdd(&deg[dst[e] * 16], 1);
    }

    {
        const float4* w4 = (const float4*)W1;
        float4* s4 = (float4*)sB;
#pragma unroll
        for (int i = 0; i < 8; ++i) s4[t + i * 256] = w4[t + i * 256];
    }
    const int r0 = (t >> 3) * 2;
    const int c0 = (t & 7) * 8;   // head = t&7, channels c0..c0+7
    float acc0[8] = {0, 0, 0, 0, 0, 0, 0, 0};
    float acc1[8] = {0, 0, 0, 0, 0, 0, 0, 0};
    for (int kb = 0; kb < 2; ++kb) {
        __syncthreads();
#pragma unroll
        for (int i = 0; i < 4; ++i) {
            int idx = t + i * 256;
            int r = idx >> 4, kc = idx & 15;
            int n = n0 + r;
            float4 v = make_float4(0.f, 0.f, 0.f, 0.f);
            if (n < N) v = ((const float4*)x)[(size_t)n * 32 + kb * 16 + kc];
            *(float4*)&sA[r * 68 + kc * 4] = v;
        }
        __syncthreads();
        const float* bptr = &sB[kb * 64 * 64];
#pragma unroll 8
        for (int kk = 0; kk < 64; ++kk) {
            float a0 = sA[r0 * 68 + kk];
            float a1 = sA[(r0 + 1) * 68 + kk];
            const float* bp = &bptr[kk * 64 + c0];
            float4 b0 = *(const float4*)bp;
            float4 b1v = *(const float4*)(bp + 4);
            acc0[0] += a0 * b0.x; acc0[1] += a0 * b0.y; acc0[2] += a0 * b0.z; acc0[3] += a0 * b0.w;
            acc0[4] += a0 * b1v.x; acc0[5] += a0 * b1v.y; acc0[6] += a0 * b1v.z; acc0[7] += a0 * b1v.w;
            acc1[0] += a1 * b0.x; acc1[1] += a1 * b0.y; acc1[2] += a1 * b0.z; acc1[3] += a1 * b0.w;
            acc1[4] += a1 * b1v.x; acc1[5] += a1 * b1v.y; acc1[6] += a1 * b1v.z; acc1[7] += a1 * b1v.w;
        }
    }
    float ps0 = 0.f, pd0 = 0.f, ps1 = 0.f, pd1 = 0.f;
#pragma unroll
    for (int i = 0; i < 8; ++i) {
        float ws = as1[c0 + i], wd = ad1[c0 + i];
        ps0 += acc0[i] * ws; pd0 += acc0[i] * wd;
        ps1 += acc1[i] * ws; pd1 += acc1[i] * wd;
    }
    int n = n0 + r0;
    int head = t & 7;
    if (n < N) {
        int q0 = 0, q1 = 0;
        q0 = __builtin_amdgcn_cvt_pk_fp8_f32(acc0[0] * S1, acc0[1] * S1, q0, false);
        q0 = __builtin_amdgcn_cvt_pk_fp8_f32(acc0[2] * S1, acc0[3] * S1, q0, true);
        q1 = __builtin_amdgcn_cvt_pk_fp8_f32(acc0[4] * S1, acc0[5] * S1, q1, false);
        q1 = __builtin_amdgcn_cvt_pk_fp8_f32(acc0[6] * S1, acc0[7] * S1, q1, true);
        uint2 p; p.x = (uint)q0; p.y = (uint)q1;
        *(uint2*)&h1f8[(size_t)n * 64 + c0] = p;
        al1s[(size_t)n * 8 + head] = ps0;
        al1d[(size_t)n * 8 + head] = pd0;
    }
    if (n + 1 < N) {
        int q0 = 0, q1 = 0;
        q0 = __builtin_amdgcn_cvt_pk_fp8_f32(acc1[0] * S1, acc1[1] * S1, q0, false);
        q0 = __builtin_amdgcn_cvt_pk_fp8_f32(acc1[2] * S1, acc1[3] * S1, q0, true);
        q1 = __builtin_amdgcn_cvt_pk_fp8_f32(acc1[4] * S1, acc1[5] * S1, q1, false);
        q1 = __builtin_amdgcn_cvt_pk_fp8_f32(acc1[6] * S1, acc1[7] * S1, q1, true);
        uint2 p; p.x = (uint)q0; p.y = (uint)q1;
        *(uint2*)&h1f8[(size_t)(n + 1) * 64 + c0] = p;
        al1s[(size_t)(n + 1) * 8 + head] = ps1;
        al1d[(size_t)(n + 1) * 8 + head] = pd1;
    }
    if (efull) {
        *(int4*)&rank[ebase] = make_int4(ra0, ra1, ra2, ra3);
        *(int4*)&rank[ebase + 4] = make_int4(ra4, ra5, ra6, ra7);
    }
}

// ---- GEMM2: h2f8[N,128](fp8,x16) = relu(x1pre+b1) @ W2[64,128], fused al2 ----
__global__ __launch_bounds__(256) void k_gemm2(const float* __restrict__ x1pre,
                                               const float* __restrict__ W2,
                                               const float* __restrict__ b1,
                                               const float* __restrict__ as2,
                                               const float* __restrict__ ad2,
                                               uchar* __restrict__ h2f8,
                                               float* __restrict__ al2s,
                                               float* __restrict__ al2d, int N) {
    __shared__ float sB[64 * 128];
    __shared__ float sA[64 * 68];
    const int t = threadIdx.x;
    const int n0 = blockIdx.x * 64;
    {
        const float4* w4 = (const float4*)W2;
        float4* s4 = (float4*)sB;
#pragma unroll
        for (int i = 0; i < 8; ++i) s4[t + i * 256] = w4[t + i * 256];
    }
#pragma unroll
    for (int i = 0; i < 4; ++i) {
        int idx = t + i * 256;
        int r = idx >> 4, kc = idx & 15;
        int n = n0 + r;
        float4 v = make_float4(0.f, 0.f, 0.f, 0.f);
        if (n < N) {
            v = ((const float4*)x1pre)[(size_t)n * 16 + kc];
            float4 bb = ((const float4*)b1)[kc];
            v.x = fmaxf(v.x + bb.x, 0.f);
            v.y = fmaxf(v.y + bb.y, 0.f);
            v.z = fmaxf(v.z + bb.z, 0.f);
            v.w = fmaxf(v.w + bb.w, 0.f);
        }
        *(float4*)&sA[r * 68 + kc * 4] = v;
    }
    __syncthreads();
    const int r0 = (t >> 3) * 2;
    const int cb = (t & 7) * 4;
    float acc0[16], acc1[16];
#pragma unroll
    for (int i = 0; i < 16; ++i) { acc0[i] = 0.f; acc1[i] = 0.f; }
#pragma unroll 4
    for (int k = 0; k < 64; ++k) {
        float a0 = sA[r0 * 68 + k];
        float a1 = sA[(r0 + 1) * 68 + k];
#pragma unroll
        for (int j = 0; j < 4; ++j) {
            float4 b = *(const float4*)&sB[k * 128 + cb + 32 * j];
            acc0[j * 4 + 0] += a0 * b.x; acc0[j * 4 + 1] += a0 * b.y;
            acc0[j * 4 + 2] += a0 * b.z; acc0[j * 4 + 3] += a0 * b.w;
            acc1[j * 4 + 0] += a1 * b.x; acc1[j * 4 + 1] += a1 * b.y;
            acc1[j * 4 + 2] += a1 * b.z; acc1[j * 4 + 3] += a1 * b.w;
        }
    }
    float ps0 = 0.f, pd0 = 0.f, ps1 = 0.f, pd1 = 0.f;
#pragma unroll
    for (int j = 0; j < 4; ++j)
#pragma unroll
        for (int i = 0; i < 4; ++i) {
            int cc = cb + 32 * j + i;
            float ws = as2[cc], wd = ad2[cc];
            ps0 += acc0[j * 4 + i] * ws; pd0 += acc0[j * 4 + i] * wd;
            ps1 += acc1[j * 4 + i] * ws; pd1 += acc1[j * 4 + i] * wd;
        }
#pragma unroll
    for (int off = 1; off < 8; off <<= 1) {
        ps0 += __shfl_xor(ps0, off); pd0 += __shfl_xor(pd0, off);
        ps1 += __shfl_xor(ps1, off); pd1 += __shfl_xor(pd1, off);
    }
    int n = n0 + r0;
    if (n < N) {
#pragma unroll
        for (int j = 0; j < 4; ++j) {
            int q = 0;
            q = __builtin_amdgcn_cvt_pk_fp8_f32(acc0[j * 4 + 0] * S2, acc0[j * 4 + 1] * S2, q, false);
            q = __builtin_amdgcn_cvt_pk_fp8_f32(acc0[j * 4 + 2] * S2, acc0[j * 4 + 3] * S2, q, true);
            *(uint*)&h2f8[(size_t)n * 128 + cb + 32 * j] = (uint)q;
        }
        if ((t & 7) == 0) { al2s[n] = ps0; al2d[n] = pd0; }
    }
    if (n + 1 < N) {
#pragma unroll
        for (int j = 0; j < 4; ++j) {
            int q = 0;
            q = __builtin_amdgcn_cvt_pk_fp8_f32(acc1[j * 4 + 0] * S2, acc1[j * 4 + 1] * S2, q, false);
            q = __builtin_amdgcn_cvt_pk_fp8_f32(acc1[j * 4 + 2] * S2, acc1[j * 4 + 3] * S2, q, true);
            *(uint*)&h2f8[(size_t)(n + 1) * 128 + cb + 32 * j] = (uint)q;
        }
        if ((t & 7) == 0) { al2s[n + 1] = ps1; al2d[n + 1] = pd1; }
    }
}

// ---------------- CSR construction (scan + fill) ----------------
__global__ void k_scan1(const int* __restrict__ deg, int* __restrict__ row_ptr,
                        int* __restrict__ bsums, int N) {
    __shared__ int sh[256];
    int t = threadIdx.x, b = blockIdx.x;
    int i = b * 256 + t;
    int v = (i < N) ? (deg[i * 16] + 1) : 0;  // +1 for self-loop; stride-16 counters
    sh[t] = v;
    __syncthreads();
    int accv = v;
    for (int off = 1; off < 256; off <<= 1) {
        int u = (t >= off) ? sh[t - off] : 0;
        __syncthreads();
        accv += u;
        sh[t] = accv;
        __syncthreads();
    }
    if (i < N) row_ptr[i] = accv - v;
    if (t == 255) bsums[b] = accv;
}

__global__ void k_scan2(int* __restrict__ bsums, int nb) {
    __shared__ int sh[512];
    int t = threadIdx.x;
    int v = (t < nb) ? bsums[t] : 0;
    sh[t] = v;
    __syncthreads();
    int accv = v;
    for (int off = 1; off < 512; off <<= 1) {
        int u = (t >= off) ? sh[t - off] : 0;
        __syncthreads();
        accv += u;
        sh[t] = accv;
        __syncthreads();
    }
    if (t < nb) bsums[t] = accv - v;
}

__global__ void k_scan3(int* __restrict__ row_ptr, const int* __restrict__ bsums,
                        const int* __restrict__ deg, int* __restrict__ col,
                        int N, int total) {
    int i = blockIdx.x * 256 + threadIdx.x;
    if (i < N) {
        int rp = row_ptr[i] + bsums[blockIdx.x];
        row_ptr[i] = rp;
        col[rp + deg[i * 16]] = i;  // self-loop at the end of row i
    }
    if (i == 0) row_ptr[N] = total;
}

__global__ __launch_bounds__(256) void k_fill(const int* __restrict__ src,
                                              const int* __restrict__ dst,
                                              const int* __restrict__ rank,
                                              const int* __restrict__ row_ptr,
                                              int* __restrict__ col, int E) {
    int base = (blockIdx.x * 256 + threadIdx.x) * 4;
    if (base + 4 <= E) {
        int4 d = *(const int4*)&dst[base];
        int4 s = *(const int4*)&src[base];
        int4 r = *(const int4*)&rank[base];
        int p0 = row_ptr[d.x] + r.x;
        int p1 = row_ptr[d.y] + r.y;
        int p2 = row_ptr[d.z] + r.z;
        int p3 = row_ptr[d.w] + r.w;
        col[p0] = s.x;
        col[p1] = s.y;
        col[p2] = s.z;
        col[p3] = s.w;
    } else {
        for (int e = base; e < E; ++e) col[row_ptr[dst[e]] + rank[e]] = src[e];
    }
}

// ---- edge1: wave/node, LDS-free; lane=(edge&7)*8+head weights, shfl handoff ----
__global__ __launch_bounds__(256) void k_edge1(const uchar* __restrict__ h1f8,
                                               const float* __restrict__ al1s,
                                               const float* __restrict__ al1d,
                                               const int* __restrict__ row_ptr,
                                               const int* __restrict__ col,
                                               float* __restrict__ x1pre, int N) {
    int node = blockIdx.x * 4 + (threadIdx.x >> 6);
    if (node >= N) return;
    const int lane = threadIdx.x & 63;
    const int e8 = lane >> 3;      // weight phase: edge-in-8group
    const int h = lane & 7;        // weight phase: head
    const int g = lane >> 4;       // gather phase: edge subgroup 0..3
    const int k4 = lane & 15;      // gather phase: channel quad (ch 4k4..4k4+3)
    const int hh = k4 >> 1;        // head of those channels
    float a_d = al1d[(size_t)node * 8 + h];
    const int s0 = row_ptr[node], s1 = row_ptr[node + 1];
    float den_part = 0.f;
    float acc[4] = {0.f, 0.f, 0.f, 0.f};
    for (int base = s0; base < s1; base += 64) {
        int idx = base + lane;
        int cidx = idx < s1 ? idx : s1 - 1;
        int my_col = col[cidx];               // one coalesced load / 64 edges
        int cnt = s1 - base; if (cnt > 64) cnt = 64;
        int cntR = (cnt + 7) & ~7;
        int i = 0;
        for (; i + 16 <= cntR; i += 16) {
            int cA = __shfl(my_col, i + g);
            int cB = __shfl(my_col, i + 4 + g);
            int cC = __shfl(my_col, i + 8 + g);
            int cD = __shfl(my_col, i + 12 + g);
            uint hA = *(const uint*)(h1f8 + (size_t)cA * 64 + k4 * 4);
            uint hB = *(const uint*)(h1f8 + (size_t)cB * 64 + k4 * 4);
            uint hC = *(const uint*)(h1f8 + (size_t)cC * 64 + k4 * 4);
            uint hD = *(const uint*)(h1f8 + (size_t)cD * 64 + k4 * 4);
            int c0 = __shfl(my_col, i + e8);
            int c1 = __shfl(my_col, i + 8 + e8);
            float e0v = al1s[(size_t)c0 * 8 + h] + a_d;
            float e1v = al1s[(size_t)c1 * 8 + h] + a_d;
            e0v = e0v > 0.f ? e0v : 0.2f * e0v;
            e1v = e1v > 0.f ? e1v : 0.2f * e1v;
            float w0 = (base + i + e8 < s1) ? __expf(e0v) : 0.f;
            float w1 = (base + i + 8 + e8 < s1) ? __expf(e1v) : 0.f;
            den_part += w0 + w1;
            float wA = __shfl(w0, g * 8 + hh);
            float wB = __shfl(w0, (4 + g) * 8 + hh);
            float wC = __shfl(w1, g * 8 + hh);
            float wD = __shfl(w1, (4 + g) * 8 + hh);
            v2f p;
            p = fp8x2f<false>(hA); acc[0] += wA * p.x; acc[1] += wA * p.y;
            p = fp8x2f<true>(hA);  acc[2] += wA * p.x; acc[3] += wA * p.y;
            p = fp8x2f<false>(hB); acc[0] += wB * p.x; acc[1] += wB * p.y;
            p = fp8x2f<true>(hB);  acc[2] += wB * p.x; acc[3] += wB * p.y;
            p = fp8x2f<false>(hC); acc[0] += wC * p.x; acc[1] += wC * p.y;
            p = fp8x2f<true>(hC);  acc[2] += wC * p.x; acc[3] += wC * p.y;
            p = fp8x2f<false>(hD); acc[0] += wD * p.x; acc[1] += wD * p.y;
            p = fp8x2f<true>(hD);  acc[2] += wD * p.x; acc[3] += wD * p.y;
        }
        if (i < cntR) {  // exactly 8 edges left
            int cA = __shfl(my_col, i + g);
            int cB = __shfl(my_col, i + 4 + g);
            uint hA = *(const uint*)(h1f8 + (size_t)cA * 64 + k4 * 4);
            uint hB = *(const uint*)(h1f8 + (size_t)cB * 64 + k4 * 4);
            int c0 = __shfl(my_col, i + e8);
            float e0v = al1s[(size_t)c0 * 8 + h] + a_d;
            e0v = e0v > 0.f ? e0v : 0.2f * e0v;
            float w0 = (base + i + e8 < s1) ? __expf(e0v) : 0.f;
            den_part += w0;
            float wA = __shfl(w0, g * 8 + hh);
            float wB = __shfl(w0, (4 + g) * 8 + hh);
            v2f p;
            p = fp8x2f<false>(hA); acc[0] += wA * p.x; acc[1] += wA * p.y;
            p = fp8x2f<true>(hA);  acc[2] += wA * p.x; acc[3] += wA * p.y;
            p = fp8x2f<false>(hB); acc[0] += wB * p.x; acc[1] += wB * p.y;
            p = fp8x2f<true>(hB);  acc[2] += wB * p.x; acc[3] += wB * p.y;
        }
    }
#pragma unroll
    for (int i = 0; i < 4; ++i) {
        acc[i] += __shfl_xor(acc[i], 16);
        acc[i] += __shfl_xor(acc[i], 32);
    }
    den_part += __shfl_xor(den_part, 8);
    den_part += __shfl_xor(den_part, 16);
    den_part += __shfl_xor(den_part, 32);
    float den = __shfl(den_part, hh);
    if (lane < 16) {
        float invd = 1.f / (den * S1);
        ((float4*)x1pre)[(size_t)node * 16 + k4] =
            make_float4(acc[0] * invd, acc[1] * invd, acc[2] * invd, acc[3] * invd);
    }
}

// ---- edge2: wave/node; 16 lanes/row uint2 fp8, 4 loads in flight ----
__global__ __launch_bounds__(256) void k_edge2(const uchar* __restrict__ h2f8,
                                               const float* __restrict__ al2s,
                                               const float* __restrict__ al2d,
                                               const int* __restrict__ row_ptr,
                                               const int* __restrict__ col,
                                               const float* __restrict__ b2,
                                               float* __restrict__ x2, int N) {
    int node = blockIdx.x * 4 + (threadIdx.x >> 6);
    if (node >= N) return;
    const int lane = threadIdx.x & 63;
    const int g = lane >> 4;    // edge group 0..3
    const int k8 = lane & 15;   // channel oct (ch 8k8..8k8+7 of 128)
    float a_d = al2d[node];
    int s0 = row_ptr[node], s1 = row_ptr[node + 1];
    float acc[8];
#pragma unroll
    for (int i = 0; i < 8; ++i) acc[i] = 0.f;
    float den = 0.f;
    for (int base = s0; base < s1; base += 64) {
        int idx = base + lane;
        int cidx = idx < s1 ? idx : s1 - 1;
        int my_col = col[cidx];
        float my_e = al2s[my_col] + a_d;
        my_e = my_e > 0.f ? my_e : 0.2f * my_e;
        float my_w = (idx < s1) ? __expf(my_e) : 0.f;
        den += my_w;
        int cnt = s1 - base; if (cnt > 64) cnt = 64;
        int cntR = (cnt + 7) & ~7;
        int i = 0;
        for (; i + 16 <= cntR; i += 16) {
            int eA = i + g, eB = i + 4 + g, eC = i + 8 + g, eD = i + 12 + g;
            int cA = __shfl(my_col, eA), cB = __shfl(my_col, eB);
            int cC = __shfl(my_col, eC), cD = __shfl(my_col, eD);
            float wA = __shfl(my_w, eA), wB = __shfl(my_w, eB);
            float wC = __shfl(my_w, eC), wD = __shfl(my_w, eD);
            uint2 hA = *(const uint2*)(h2f8 + (size_t)cA * 128 + k8 * 8);
            uint2 hB = *(const uint2*)(h2f8 + (size_t)cB * 128 + k8 * 8);
            uint2 hC = *(const uint2*)(h2f8 + (size_t)cC * 128 + k8 * 8);
            uint2 hD = *(const uint2*)(h2f8 + (size_t)cD * 128 + k8 * 8);
            v2f p;
            p = fp8x2f<false>(hA.x); acc[0] += wA * p.x; acc[1] += wA * p.y;
            p = fp8x2f<true>(hA.x);  acc[2] += wA * p.x; acc[3] += wA * p.y;
            p = fp8x2f<false>(hA.y); acc[4] += wA * p.x; acc[5] += wA * p.y;
            p = fp8x2f<true>(hA.y);  acc[6] += wA * p.x; acc[7] += wA * p.y;
            p = fp8x2f<false>(hB.x); acc[0] += wB * p.x; acc[1] += wB * p.y;
            p = fp8x2f<true>(hB.x);  acc[2] += wB * p.x; acc[3] += wB * p.y;
            p = fp8x2f<false>(hB.y); acc[4] += wB * p.x; acc[5] += wB * p.y;
            p = fp8x2f<true>(hB.y);  acc[6] += wB * p.x; acc[7] += wB * p.y;
            p = fp8x2f<false>(hC.x); acc[0] += wC * p.x; acc[1] += wC * p.y;
            p = fp8x2f<true>(hC.x);  acc[2] += wC * p.x; acc[3] += wC * p.y;
            p = fp8x2f<false>(hC.y); acc[4] += wC * p.x; acc[5] += wC * p.y;
            p = fp8x2f<true>(hC.y);  acc[6] += wC * p.x; acc[7] += wC * p.y;
            p = fp8x2f<false>(hD.x); acc[0] += wD * p.x; acc[1] += wD * p.y;
            p = fp8x2f<true>(hD.x);  acc[2] += wD * p.x; acc[3] += wD * p.y;
            p = fp8x2f<false>(hD.y); acc[4] += wD * p.x; acc[5] += wD * p.y;
            p = fp8x2f<true>(hD.y);  acc[6] += wD * p.x; acc[7] += wD * p.y;
        }
        if (i < cntR) {  // exactly 8 edges left
            int eA = i + g, eB = i + 4 + g;
            int cA = __shfl(my_col, eA), cB = __shfl(my_col, eB);
            float wA = __shfl(my_w, eA), wB = __shfl(my_w, eB);
            uint2 hA = *(const uint2*)(h2f8 + (size_t)cA * 128 + k8 * 8);
            uint2 hB = *(const uint2*)(h2f8 + (size_t)cB * 128 + k8 * 8);
            v2f p;
            p = fp8x2f<false>(hA.x); acc[0] += wA * p.x; acc[1] += wA * p.y;
            p = fp8x2f<true>(hA.x);  acc[2] += wA * p.x; acc[3] += wA * p.y;
            p = fp8x2f<false>(hA.y); acc[4] += wA * p.x; acc[5] += wA * p.y;
            p = fp8x2f<true>(hA.y);  acc[6] += wA * p.x; acc[7] += wA * p.y;
            p = fp8x2f<false>(hB.x); acc[0] += wB * p.x; acc[1] += wB * p.y;
            p = fp8x2f<true>(hB.x);  acc[2] += wB * p.x; acc[3] += wB * p.y;
            p = fp8x2f<false>(hB.y); acc[4] += wB * p.x; acc[5] += wB * p.y;
            p = fp8x2f<true>(hB.y);  acc[6] += wB * p.x; acc[7] += wB * p.y;
        }
    }
#pragma unroll
    for (int off = 1; off < 64; off <<= 1) den += __shfl_xor(den, off);
#pragma unroll
    for (int i = 0; i < 8; ++i) {
        acc[i] += __shfl_xor(acc[i], 16);
        acc[i] += __shfl_xor(acc[i], 32);
    }
    if (lane < 16) {
        float invd = 1.f / (den * S2);
        const float4* bb = (const float4*)b2;
        float4 o0 = bb[k8 * 2], o1 = bb[k8 * 2 + 1];
        float4* dst = (float4*)(x2 + (size_t)node * 128 + k8 * 8);
        dst[0] = make_float4(acc[0] * invd + o0.x, acc[1] * invd + o0.y,
                             acc[2] * invd + o0.z, acc[3] * invd + o0.w);
        dst[1] = make_float4(acc[4] * invd + o1.x, acc[5] * invd + o1.y,
                             acc[6] * invd + o1.z, acc[7] * invd + o1.w);
    }
}

// ---- mean pool over sorted batch (run-length chunked atomics) ----
__global__ __launch_bounds__(128) void k_pool(const float* __restrict__ x2,
                                              const int* __restrict__ batch,
                                              float* __restrict__ pooled,
                                              float* __restrict__ cnt, int N) {
    int t = threadIdx.x;
    int nstart = blockIdx.x * 128;
    if (nstart >= N) return;
    int nend = nstart + 128;
    if (nend > N) nend = N;
    float acc = 0.f;
    int cur = batch[nstart];
    int count = 0;
    for (int n = nstart; n < nend; ++n) {
        int g = batch[n];
        if (g != cur) {
            atomicAdd(&pooled[(size_t)cur * 128 + t], acc);
            if (t == 0) atomicAdd(&cnt[cur], (float)count);
            acc = 0.f;
            count = 0;
            cur = g;
        }
        acc += x2[(size_t)n * 128 + t];
        ++count;
    }
    atomicAdd(&pooled[(size_t)cur * 128 + t], acc);
    if (t == 0) atomicAdd(&cnt[cur], (float)count);
}

// ---- FC + log_softmax: one wave per graph ----
__global__ __launch_bounds__(64) void k_fc(const float* __restrict__ pooled,
                                           const float* __restrict__ cnt,
                                           const float* __restrict__ fcw,
                                           const float* __restrict__ fcb,
                                           float* __restrict__ out, int G) {
    int g = blockIdx.x;
    int c = threadIdx.x;
    float2 p = ((const float2*)pooled)[(size_t)g * 64 + c];
    float inv = 1.f / fmaxf(cnt[g], 1.f);
    p.x *= inv; p.y *= inv;
    float l[10];
#pragma unroll
    for (int j = 0; j < 10; ++j)
        l[j] = p.x * fcw[(2 * c) * 10 + j] + p.y * fcw[(2 * c + 1) * 10 + j];
#pragma unroll
    for (int j = 0; j < 10; ++j)
        for (int off = 1; off < 64; off <<= 1) l[j] += __shfl_xor(l[j], off);
    if (c == 0) {
        float lj[10];
        float m = -1e30f;
#pragma unroll
        for (int j = 0; j < 10; ++j) {
            lj[j] = l[j] + fcb[j];
            m = fmaxf(m, lj[j]);
        }
        float s = 0.f;
#pragma unroll
        for (int j = 0; j < 10; ++j) s += expf(lj[j] - m);
        float ls = logf(s);
#pragma unroll
        for (int j = 0; j < 10; ++j) out[(size_t)g * 10 + j] = lj[j] - m - ls;
    }
}

extern "C" void kernel_launch(void* const* d_in, const int* in_sizes, int n_in,
                              void* d_out, int out_size, void* d_ws, size_t ws_size,
                              hipStream_t stream) {
    const float* x     = (const float*)d_in[0];
    const int*   ei    = (const int*)d_in[1];
    const int*   batch = (const int*)d_in[2];
    const float* W1    = (const float*)d_in[3];
    const float* as1   = (const float*)d_in[4];
    const float* ad1   = (const float*)d_in[5];
    const float* b1    = (const float*)d_in[6];
    const float* W2    = (const float*)d_in[7];
    const float* as2   = (const float*)d_in[8];
    const float* ad2   = (const float*)d_in[9];
    const float* b2    = (const float*)d_in[10];
    const float* fcw   = (const float*)d_in[11];
    const float* fcb   = (const float*)d_in[12];
    float* out = (float*)d_out;

    const int N = in_sizes[0] / 128;
    const int E = in_sizes[1] / 2;
    const int G = out_size / 10;
    const int* srcp = ei;
    const int* dstp = ei + E;

    // workspace (float units):
    //   [0,16N)     h1f8 (N*64 fp8)   -- dead after k_edge1
    //   [16N,80N)   x1pre (f32 N*64)  -- dead after k_gemm2
    //   [0,128N)    x2 (f32 N*128)    -- aliases dead h1f8/x1pre
    //   [128N,160N) h2f8 (N*128 fp8)
    //   [160N,168N) al1s  [168N,176N) al1d  [176N,177N) al2s  [177N,178N) al2d
    //   [178N,...)  pooled[G*128], cnt[G], deg[16N] (stride-16), row_ptr, col, rank, bsums
    float* wf = (float*)d_ws;
    uchar* h1f8   = (uchar*)wf;
    float* x1pre  = wf + (size_t)N * 16;
    float* x2     = wf;
    uchar* h2f8   = (uchar*)(wf + (size_t)N * 128);
    float* al1s_  = wf + (size_t)N * 160;
    float* al1d_  = wf + (size_t)N * 168;
    float* al2s_  = wf + (size_t)N * 176;
    float* al2d_  = wf + (size_t)N * 177;
    float* pooled = wf + (size_t)N * 178;
    float* cnt    = pooled + (size_t)G * 128;
    int* deg      = (int*)(cnt + G);             // [16N] padded counters (1 per 64B line)
    int* row_ptr  = deg + (size_t)16 * N;        // [N+1]
    int* col      = row_ptr + N + 1;             // [E+N]
    int* rank     = col + (size_t)E + N;         // [E]
    int* bsums    = rank + E;                    // [<=512]

    size_t zbytes = ((size_t)G * 128 + G + (size_t)16 * N) * sizeof(float);
    (void)hipMemsetAsync(pooled, 0, zbytes, stream);

    const int nb64 = (N + 63) / 64;     // 1563 blocks; 1563*2048 >= E covers edge chunks
    const int nb4  = (N + 3) / 4;
    const int nbS  = (N + 255) / 256;   // <= 512 for k_scan2
    const int nbP  = (N + 127) / 128;
    const int nbE4 = (E + 1023) / 1024; // 4 edges/thread

    k_gemm1<<<nb64, 256, 0, stream>>>(x, W1, as1, ad1, h1f8, al1s_, al1d_,
                                      dstp, deg, rank, E, N);
    k_scan1<<<nbS, 256, 0, stream>>>(deg, row_ptr, bsums, N);
    k_scan2<<<1, 512, 0, stream>>>(bsums, nbS);
    k_scan3<<<nbS, 256, 0, stream>>>(row_ptr, bsums, deg, col, N, E + N);
    k_fill<<<nbE4, 256, 0, stream>>>(srcp, dstp, rank, row_ptr, col, E);
    k_edge1<<<nb4, 256, 0, stream>>>(h1f8, al1s_, al1d_, row_ptr, col, x1pre, N);
    k_gemm2<<<nb64, 256, 0, stream>>>(x1pre, W2, b1, as2, ad2, h2f8, al2s_, al2d_, N);
    k_edge2<<<nb4, 256, 0, stream>>>(h2f8, al2s_, al2d_, row_ptr, col, b2, x2, N);
    k_pool<<<nbP, 128, 0, stream>>>(x2, batch, pooled, cnt, N);
    k_fc<<<G, 64, 0, stream>>>(pooled, cnt, fcw, fcb, out, G);
}

// Round 13
// 362.890 us; speedup vs baseline: 1.0742x; 1.0742x over previous
//
#include <hip/hip_runtime.h>
#include <math.h>

typedef unsigned int uint;
typedef unsigned short ushort;
typedef unsigned char uchar;
typedef __attribute__((ext_vector_type(2))) float v2f;

#define S1 4.0f
#define S2 16.0f

template <bool HI>
__device__ inline v2f fp8x2f(uint u) {
    return __builtin_amdgcn_cvt_pk_f32_fp8((int)u, HI);
}

// ---- GEMM1: h1f8[N,64](fp8,x4) = x[N,128] @ W1[128,64], fused al1s/al1d ----
__global__ __launch_bounds__(256) void k_gemm1(const float* __restrict__ x,
                                               const float* __restrict__ W1,
                                               const float* __restrict__ as1,
                                               const float* __restrict__ ad1,
                                               uchar* __restrict__ h1f8,
                                               float* __restrict__ al1s,
                                               float* __restrict__ al1d, int N) {
    __shared__ float sB[128 * 64];
    __shared__ float sA[64 * 68];
    const int t = threadIdx.x;
    const int n0 = blockIdx.x * 64;
    {
        const float4* w4 = (const float4*)W1;
        float4* s4 = (float4*)sB;
#pragma unroll
        for (int i = 0; i < 8; ++i) s4[t + i * 256] = w4[t + i * 256];
    }
    const int r0 = (t >> 3) * 2;
    const int c0 = (t & 7) * 8;   // head = t&7, channels c0..c0+7
    float acc0[8] = {0, 0, 0, 0, 0, 0, 0, 0};
    float acc1[8] = {0, 0, 0, 0, 0, 0, 0, 0};
    for (int kb = 0; kb < 2; ++kb) {
        __syncthreads();
#pragma unroll
        for (int i = 0; i < 4; ++i) {
            int idx = t + i * 256;
            int r = idx >> 4, kc = idx & 15;
            int n = n0 + r;
            float4 v = make_float4(0.f, 0.f, 0.f, 0.f);
            if (n < N) v = ((const float4*)x)[(size_t)n * 32 + kb * 16 + kc];
            *(float4*)&sA[r * 68 + kc * 4] = v;
        }
        __syncthreads();
        const float* bptr = &sB[kb * 64 * 64];
#pragma unroll 8
        for (int kk = 0; kk < 64; ++kk) {
            float a0 = sA[r0 * 68 + kk];
            float a1 = sA[(r0 + 1) * 68 + kk];
            const float* bp = &bptr[kk * 64 + c0];
            float4 b0 = *(const float4*)bp;
            float4 b1v = *(const float4*)(bp + 4);
            acc0[0] += a0 * b0.x; acc0[1] += a0 * b0.y; acc0[2] += a0 * b0.z; acc0[3] += a0 * b0.w;
            acc0[4] += a0 * b1v.x; acc0[5] += a0 * b1v.y; acc0[6] += a0 * b1v.z; acc0[7] += a0 * b1v.w;
            acc1[0] += a1 * b0.x; acc1[1] += a1 * b0.y; acc1[2] += a1 * b0.z; acc1[3] += a1 * b0.w;
            acc1[4] += a1 * b1v.x; acc1[5] += a1 * b1v.y; acc1[6] += a1 * b1v.z; acc1[7] += a1 * b1v.w;
        }
    }
    float ps0 = 0.f, pd0 = 0.f, ps1 = 0.f, pd1 = 0.f;
#pragma unroll
    for (int i = 0; i < 8; ++i) {
        float ws = as1[c0 + i], wd = ad1[c0 + i];
        ps0 += acc0[i] * ws; pd0 += acc0[i] * wd;
        ps1 += acc1[i] * ws; pd1 += acc1[i] * wd;
    }
    int n = n0 + r0;
    int head = t & 7;
    if (n < N) {
        int q0 = 0, q1 = 0;
        q0 = __builtin_amdgcn_cvt_pk_fp8_f32(acc0[0] * S1, acc0[1] * S1, q0, false);
        q0 = __builtin_amdgcn_cvt_pk_fp8_f32(acc0[2] * S1, acc0[3] * S1, q0, true);
        q1 = __builtin_amdgcn_cvt_pk_fp8_f32(acc0[4] * S1, acc0[5] * S1, q1, false);
        q1 = __builtin_amdgcn_cvt_pk_fp8_f32(acc0[6] * S1, acc0[7] * S1, q1, true);
        uint2 p; p.x = (uint)q0; p.y = (uint)q1;
        *(uint2*)&h1f8[(size_t)n * 64 + c0] = p;
        al1s[(size_t)n * 8 + head] = ps0;
        al1d[(size_t)n * 8 + head] = pd0;
    }
    if (n + 1 < N) {
        int q0 = 0, q1 = 0;
        q0 = __builtin_amdgcn_cvt_pk_fp8_f32(acc1[0] * S1, acc1[1] * S1, q0, false);
        q0 = __builtin_amdgcn_cvt_pk_fp8_f32(acc1[2] * S1, acc1[3] * S1, q0, true);
        q1 = __builtin_amdgcn_cvt_pk_fp8_f32(acc1[4] * S1, acc1[5] * S1, q1, false);
        q1 = __builtin_amdgcn_cvt_pk_fp8_f32(acc1[6] * S1, acc1[7] * S1, q1, true);
        uint2 p; p.x = (uint)q0; p.y = (uint)q1;
        *(uint2*)&h1f8[(size_t)(n + 1) * 64 + c0] = p;
        al1s[(size_t)(n + 1) * 8 + head] = ps1;
        al1d[(size_t)(n + 1) * 8 + head] = pd1;
    }
}

// ---- GEMM2: h2f8[N,128](fp8,x16) = relu(x1pre+b1) @ W2[64,128], fused al2 ----
__global__ __launch_bounds__(256) void k_gemm2(const float* __restrict__ x1pre,
                                               const float* __restrict__ W2,
                                               const float* __restrict__ b1,
                                               const float* __restrict__ as2,
                                               const float* __restrict__ ad2,
                                               uchar* __restrict__ h2f8,
                                               float* __restrict__ al2s,
                                               float* __restrict__ al2d, int N) {
    __shared__ float sB[64 * 128];
    __shared__ float sA[64 * 68];
    const int t = threadIdx.x;
    const int n0 = blockIdx.x * 64;
    {
        const float4* w4 = (const float4*)W2;
        float4* s4 = (float4*)sB;
#pragma unroll
        for (int i = 0; i < 8; ++i) s4[t + i * 256] = w4[t + i * 256];
    }
#pragma unroll
    for (int i = 0; i < 4; ++i) {
        int idx = t + i * 256;
        int r = idx >> 4, kc = idx & 15;
        int n = n0 + r;
        float4 v = make_float4(0.f, 0.f, 0.f, 0.f);
        if (n < N) {
            v = ((const float4*)x1pre)[(size_t)n * 16 + kc];
            float4 bb = ((const float4*)b1)[kc];
            v.x = fmaxf(v.x + bb.x, 0.f);
            v.y = fmaxf(v.y + bb.y, 0.f);
            v.z = fmaxf(v.z + bb.z, 0.f);
            v.w = fmaxf(v.w + bb.w, 0.f);
        }
        *(float4*)&sA[r * 68 + kc * 4] = v;
    }
    __syncthreads();
    const int r0 = (t >> 3) * 2;
    const int cb = (t & 7) * 4;
    float acc0[16], acc1[16];
#pragma unroll
    for (int i = 0; i < 16; ++i) { acc0[i] = 0.f; acc1[i] = 0.f; }
#pragma unroll 4
    for (int k = 0; k < 64; ++k) {
        float a0 = sA[r0 * 68 + k];
        float a1 = sA[(r0 + 1) * 68 + k];
#pragma unroll
        for (int j = 0; j < 4; ++j) {
            float4 b = *(const float4*)&sB[k * 128 + cb + 32 * j];
            acc0[j * 4 + 0] += a0 * b.x; acc0[j * 4 + 1] += a0 * b.y;
            acc0[j * 4 + 2] += a0 * b.z; acc0[j * 4 + 3] += a0 * b.w;
            acc1[j * 4 + 0] += a1 * b.x; acc1[j * 4 + 1] += a1 * b.y;
            acc1[j * 4 + 2] += a1 * b.z; acc1[j * 4 + 3] += a1 * b.w;
        }
    }
    float ps0 = 0.f, pd0 = 0.f, ps1 = 0.f, pd1 = 0.f;
#pragma unroll
    for (int j = 0; j < 4; ++j)
#pragma unroll
        for (int i = 0; i < 4; ++i) {
            int cc = cb + 32 * j + i;
            float ws = as2[cc], wd = ad2[cc];
            ps0 += acc0[j * 4 + i] * ws; pd0 += acc0[j * 4 + i] * wd;
            ps1 += acc1[j * 4 + i] * ws; pd1 += acc1[j * 4 + i] * wd;
        }
#pragma unroll
    for (int off = 1; off < 8; off <<= 1) {
        ps0 += __shfl_xor(ps0, off); pd0 += __shfl_xor(pd0, off);
        ps1 += __shfl_xor(ps1, off); pd1 += __shfl_xor(pd1, off);
    }
    int n = n0 + r0;
    if (n < N) {
#pragma unroll
        for (int j = 0; j < 4; ++j) {
            int q = 0;
            q = __builtin_amdgcn_cvt_pk_fp8_f32(acc0[j * 4 + 0] * S2, acc0[j * 4 + 1] * S2, q, false);
            q = __builtin_amdgcn_cvt_pk_fp8_f32(acc0[j * 4 + 2] * S2, acc0[j * 4 + 3] * S2, q, true);
            *(uint*)&h2f8[(size_t)n * 128 + cb + 32 * j] = (uint)q;
        }
        if ((t & 7) == 0) { al2s[n] = ps0; al2d[n] = pd0; }
    }
    if (n + 1 < N) {
#pragma unroll
        for (int j = 0; j < 4; ++j) {
            int q = 0;
            q = __builtin_amdgcn_cvt_pk_fp8_f32(acc1[j * 4 + 0] * S2, acc1[j * 4 + 1] * S2, q, false);
            q = __builtin_amdgcn_cvt_pk_fp8_f32(acc1[j * 4 + 2] * S2, acc1[j * 4 + 3] * S2, q, true);
            *(uint*)&h2f8[(size_t)(n + 1) * 128 + cb + 32 * j] = (uint)q;
        }
        if ((t & 7) == 0) { al2s[n + 1] = ps1; al2d[n + 1] = pd1; }
    }
}

// ========== atomic-free CSR build: two-level counting sort ==========
// buckets: dst >> 7 (128 nodes each). All fine-grained atomics are LDS-local.

// pass A: per-block LDS histogram over buckets
__global__ __launch_bounds__(256) void k_hist(const int* __restrict__ dst,
                                              int* __restrict__ counts,
                                              int E, int CH, int NB) {
    __shared__ int hist[784];
    int t = threadIdx.x, b = blockIdx.x;
    for (int k = t; k < NB; k += 256) hist[k] = 0;
    __syncthreads();
    int e0 = b * CH;
    int e1 = e0 + CH; if (e1 > E) e1 = E;
    for (int e = e0 + t; e < e1; e += 256)
        atomicAdd(&hist[dst[e] >> 7], 1);
    __syncthreads();
    for (int k = t; k < NB; k += 256) counts[(size_t)b * NB + k] = hist[k];
}

// pass B: per-bucket exclusive scan over blocks (one block per bucket)
__global__ __launch_bounds__(256) void k_bscan(int* __restrict__ counts,
                                               int* __restrict__ btot,
                                               int C, int NB) {
    __shared__ int sh[256];
    int t = threadIdx.x, k = blockIdx.x;
    int v[4];
#pragma unroll
    for (int i = 0; i < 4; ++i) {
        int b = t * 4 + i;
        v[i] = (b < C) ? counts[(size_t)b * NB + k] : 0;
    }
    int s = v[0] + v[1] + v[2] + v[3];
    sh[t] = s;
    __syncthreads();
    int accv = s;
    for (int off = 1; off < 256; off <<= 1) {
        int u = (t >= off) ? sh[t - off] : 0;
        __syncthreads();
        accv += u;
        sh[t] = accv;
        __syncthreads();
    }
    int excl = accv - s;
#pragma unroll
    for (int i = 0; i < 4; ++i) {
        int b = t * 4 + i;
        if (b < C) counts[(size_t)b * NB + k] = excl;
        excl += v[i];
    }
    if (t == 255) btot[k] = accv;
}

// pass C: bucket base offsets (single block; NB <= 1024)
__global__ void k_bscan2(const int* __restrict__ btot, int* __restrict__ bbase,
                         int NB, int E) {
    __shared__ int sh[1024];
    int t = threadIdx.x;
    int v = (t < NB) ? btot[t] : 0;
    sh[t] = v;
    __syncthreads();
    int accv = v;
    for (int off = 1; off < 1024; off <<= 1) {
        int u = (t >= off) ? sh[t - off] : 0;
        __syncthreads();
        accv += u;
        sh[t] = accv;
        __syncthreads();
    }
    if (t < NB) bbase[t] = accv - v;
    if (t == 0) bbase[NB] = E;
}

// pass D: scatter edges into bucket-sorted ebuf (LDS returning atomics only)
__global__ __launch_bounds__(256) void k_bucket(const int* __restrict__ src,
                                                const int* __restrict__ dst,
                                                const int* __restrict__ counts,
                                                const int* __restrict__ bbase,
                                                int2* __restrict__ ebuf,
                                                int E, int CH, int NB) {
    __shared__ int pos[784];
    int t = threadIdx.x, b = blockIdx.x;
    for (int k = t; k < NB; k += 256)
        pos[k] = bbase[k] + counts[(size_t)b * NB + k];
    __syncthreads();
    int e0 = b * CH;
    int e1 = e0 + CH; if (e1 > E) e1 = E;
    for (int e = e0 + t; e < e1; e += 256) {
        int d = dst[e], s = src[e];
        int p = atomicAdd(&pos[d >> 7], 1);
        ebuf[p] = make_int2(s, d);
    }
}

// pass E: per-bucket fine CSR (count -> scan -> row_ptr + self-loop + local scatter)
__global__ __launch_bounds__(256) void k_csr(const int* __restrict__ bbase,
                                             const int2* __restrict__ ebuf,
                                             int* __restrict__ row_ptr,
                                             int* __restrict__ col,
                                             int N, int E) {
    __shared__ int cnt[128];
    __shared__ int fill[128];
    __shared__ int rowb[128];
    __shared__ int sh[256];
    int t = threadIdx.x, k = blockIdx.x;
    int lo = bbase[k], hi = bbase[k + 1];
    int nlo = k << 7;
    int nn = N - nlo; if (nn > 128) nn = 128;
    if (t < 128) { cnt[t] = 0; fill[t] = 0; }
    __syncthreads();
    for (int i = lo + t; i < hi; i += 256)
        atomicAdd(&cnt[ebuf[i].y & 127], 1);
    __syncthreads();
    int v = (t < nn) ? (cnt[t] + 1) : 0;  // +1 self-loop slot
    sh[t] = v;
    __syncthreads();
    int accv = v;
    for (int off = 1; off < 256; off <<= 1) {
        int u = (t >= off) ? sh[t - off] : 0;
        __syncthreads();
        accv += u;
        sh[t] = accv;
        __syncthreads();
    }
    int fbase = lo + nlo;  // global final offset = edge prefix + self-loop prefix
    if (t < nn) {
        int rb = fbase + accv - v;
        rowb[t] = rb;
        row_ptr[nlo + t] = rb;
        col[rb + cnt[t]] = nlo + t;  // self-loop at end of row
    }
    if (k == 0 && t == 0) row_ptr[N] = E + N;
    __syncthreads();
    for (int i = lo + t; i < hi; i += 256) {
        int2 e = ebuf[i];
        int j = e.y & 127;
        int r = atomicAdd(&fill[j], 1);
        col[rowb[j] + r] = e.x;
    }
}

// ---- edge1: wave/node, LDS-free; lane=(edge&7)*8+head weights, shfl handoff ----
__global__ __launch_bounds__(256) void k_edge1(const uchar* __restrict__ h1f8,
                                               const float* __restrict__ al1s,
                                               const float* __restrict__ al1d,
                                               const int* __restrict__ row_ptr,
                                               const int* __restrict__ col,
                                               float* __restrict__ x1pre, int N) {
    int node = blockIdx.x * 4 + (threadIdx.x >> 6);
    if (node >= N) return;
    const int lane = threadIdx.x & 63;
    const int e8 = lane >> 3;      // weight phase: edge-in-8group
    const int h = lane & 7;        // weight phase: head
    const int g = lane >> 4;       // gather phase: edge subgroup 0..3
    const int k4 = lane & 15;      // gather phase: channel quad (ch 4k4..4k4+3)
    const int hh = k4 >> 1;        // head of those channels
    float a_d = al1d[(size_t)node * 8 + h];
    const int s0 = row_ptr[node], s1 = row_ptr[node + 1];
    float den_part = 0.f;
    float acc[4] = {0.f, 0.f, 0.f, 0.f};
    for (int base = s0; base < s1; base += 64) {
        int idx = base + lane;
        int cidx = idx < s1 ? idx : s1 - 1;
        int my_col = col[cidx];               // one coalesced load / 64 edges
        int cnt = s1 - base; if (cnt > 64) cnt = 64;
        int cntR = (cnt + 7) & ~7;
        int i = 0;
        for (; i + 16 <= cntR; i += 16) {
            int cA = __shfl(my_col, i + g);
            int cB = __shfl(my_col, i + 4 + g);
            int cC = __shfl(my_col, i + 8 + g);
            int cD = __shfl(my_col, i + 12 + g);
            uint hA = *(const uint*)(h1f8 + (size_t)cA * 64 + k4 * 4);
            uint hB = *(const uint*)(h1f8 + (size_t)cB * 64 + k4 * 4);
            uint hC = *(const uint*)(h1f8 + (size_t)cC * 64 + k4 * 4);
            uint hD = *(const uint*)(h1f8 + (size_t)cD * 64 + k4 * 4);
            int c0 = __shfl(my_col, i + e8);
            int c1 = __shfl(my_col, i + 8 + e8);
            float e0v = al1s[(size_t)c0 * 8 + h] + a_d;
            float e1v = al1s[(size_t)c1 * 8 + h] + a_d;
            e0v = e0v > 0.f ? e0v : 0.2f * e0v;
            e1v = e1v > 0.f ? e1v : 0.2f * e1v;
            float w0 = (base + i + e8 < s1) ? __expf(e0v) : 0.f;
            float w1 = (base + i + 8 + e8 < s1) ? __expf(e1v) : 0.f;
            den_part += w0 + w1;
            float wA = __shfl(w0, g * 8 + hh);
            float wB = __shfl(w0, (4 + g) * 8 + hh);
            float wC = __shfl(w1, g * 8 + hh);
            float wD = __shfl(w1, (4 + g) * 8 + hh);
            v2f p;
            p = fp8x2f<false>(hA); acc[0] += wA * p.x; acc[1] += wA * p.y;
            p = fp8x2f<true>(hA);  acc[2] += wA * p.x; acc[3] += wA * p.y;
            p = fp8x2f<false>(hB); acc[0] += wB * p.x; acc[1] += wB * p.y;
            p = fp8x2f<true>(hB);  acc[2] += wB * p.x; acc[3] += wB * p.y;
            p = fp8x2f<false>(hC); acc[0] += wC * p.x; acc[1] += wC * p.y;
            p = fp8x2f<true>(hC);  acc[2] += wC * p.x; acc[3] += wC * p.y;
            p = fp8x2f<false>(hD); acc[0] += wD * p.x; acc[1] += wD * p.y;
            p = fp8x2f<true>(hD);  acc[2] += wD * p.x; acc[3] += wD * p.y;
        }
        if (i < cntR) {  // exactly 8 edges left
            int cA = __shfl(my_col, i + g);
            int cB = __shfl(my_col, i + 4 + g);
            uint hA = *(const uint*)(h1f8 + (size_t)cA * 64 + k4 * 4);
            uint hB = *(const uint*)(h1f8 + (size_t)cB * 64 + k4 * 4);
            int c0 = __shfl(my_col, i + e8);
            float e0v = al1s[(size_t)c0 * 8 + h] + a_d;
            e0v = e0v > 0.f ? e0v : 0.2f * e0v;
            float w0 = (base + i + e8 < s1) ? __expf(e0v) : 0.f;
            den_part += w0;
            float wA = __shfl(w0, g * 8 + hh);
            float wB = __shfl(w0, (4 + g) * 8 + hh);
            v2f p;
            p = fp8x2f<false>(hA); acc[0] += wA * p.x; acc[1] += wA * p.y;
            p = fp8x2f<true>(hA);  acc[2] += wA * p.x; acc[3] += wA * p.y;
            p = fp8x2f<false>(hB); acc[0] += wB * p.x; acc[1] += wB * p.y;
            p = fp8x2f<true>(hB);  acc[2] += wB * p.x; acc[3] += wB * p.y;
        }
    }
#pragma unroll
    for (int i = 0; i < 4; ++i) {
        acc[i] += __shfl_xor(acc[i], 16);
        acc[i] += __shfl_xor(acc[i], 32);
    }
    den_part += __shfl_xor(den_part, 8);
    den_part += __shfl_xor(den_part, 16);
    den_part += __shfl_xor(den_part, 32);
    float den = __shfl(den_part, hh);
    if (lane < 16) {
        float invd = 1.f / (den * S1);
        ((float4*)x1pre)[(size_t)node * 16 + k4] =
            make_float4(acc[0] * invd, acc[1] * invd, acc[2] * invd, acc[3] * invd);
    }
}

// ---- edge2: wave/node; 16 lanes/row uint2 fp8, 4 loads in flight ----
__global__ __launch_bounds__(256) void k_edge2(const uchar* __restrict__ h2f8,
                                               const float* __restrict__ al2s,
                                               const float* __restrict__ al2d,
                                               const int* __restrict__ row_ptr,
                                               const int* __restrict__ col,
                                               const float* __restrict__ b2,
                                               float* __restrict__ x2, int N) {
    int node = blockIdx.x * 4 + (threadIdx.x >> 6);
    if (node >= N) return;
    const int lane = threadIdx.x & 63;
    const int g = lane >> 4;    // edge group 0..3
    const int k8 = lane & 15;   // channel oct (ch 8k8..8k8+7 of 128)
    float a_d = al2d[node];
    int s0 = row_ptr[node], s1 = row_ptr[node + 1];
    float acc[8];
#pragma unroll
    for (int i = 0; i < 8; ++i) acc[i] = 0.f;
    float den = 0.f;
    for (int base = s0; base < s1; base += 64) {
        int idx = base + lane;
        int cidx = idx < s1 ? idx : s1 - 1;
        int my_col = col[cidx];
        float my_e = al2s[my_col] + a_d;
        my_e = my_e > 0.f ? my_e : 0.2f * my_e;
        float my_w = (idx < s1) ? __expf(my_e) : 0.f;
        den += my_w;
        int cnt = s1 - base; if (cnt > 64) cnt = 64;
        int cntR = (cnt + 7) & ~7;
        int i = 0;
        for (; i + 16 <= cntR; i += 16) {
            int eA = i + g, eB = i + 4 + g, eC = i + 8 + g, eD = i + 12 + g;
            int cA = __shfl(my_col, eA), cB = __shfl(my_col, eB);
            int cC = __shfl(my_col, eC), cD = __shfl(my_col, eD);
            float wA = __shfl(my_w, eA), wB = __shfl(my_w, eB);
            float wC = __shfl(my_w, eC), wD = __shfl(my_w, eD);
            uint2 hA = *(const uint2*)(h2f8 + (size_t)cA * 128 + k8 * 8);
            uint2 hB = *(const uint2*)(h2f8 + (size_t)cB * 128 + k8 * 8);
            uint2 hC = *(const uint2*)(h2f8 + (size_t)cC * 128 + k8 * 8);
            uint2 hD = *(const uint2*)(h2f8 + (size_t)cD * 128 + k8 * 8);
            v2f p;
            p = fp8x2f<false>(hA.x); acc[0] += wA * p.x; acc[1] += wA * p.y;
            p = fp8x2f<true>(hA.x);  acc[2] += wA * p.x; acc[3] += wA * p.y;
            p = fp8x2f<false>(hA.y); acc[4] += wA * p.x; acc[5] += wA * p.y;
            p = fp8x2f<true>(hA.y);  acc[6] += wA * p.x; acc[7] += wA * p.y;
            p = fp8x2f<false>(hB.x); acc[0] += wB * p.x; acc[1] += wB * p.y;
            p = fp8x2f<true>(hB.x);  acc[2] += wB * p.x; acc[3] += wB * p.y;
            p = fp8x2f<false>(hB.y); acc[4] += wB * p.x; acc[5] += wB * p.y;
            p = fp8x2f<true>(hB.y);  acc[6] += wB * p.x; acc[7] += wB * p.y;
            p = fp8x2f<false>(hC.x); acc[0] += wC * p.x; acc[1] += wC * p.y;
            p = fp8x2f<true>(hC.x);  acc[2] += wC * p.x; acc[3] += wC * p.y;
            p = fp8x2f<false>(hC.y); acc[4] += wC * p.x; acc[5] += wC * p.y;
            p = fp8x2f<true>(hC.y);  acc[6] += wC * p.x; acc[7] += wC * p.y;
            p = fp8x2f<false>(hD.x); acc[0] += wD * p.x; acc[1] += wD * p.y;
            p = fp8x2f<true>(hD.x);  acc[2] += wD * p.x; acc[3] += wD * p.y;
            p = fp8x2f<false>(hD.y); acc[4] += wD * p.x; acc[5] += wD * p.y;
            p = fp8x2f<true>(hD.y);  acc[6] += wD * p.x; acc[7] += wD * p.y;
        }
        if (i < cntR) {  // exactly 8 edges left
            int eA = i + g, eB = i + 4 + g;
            int cA = __shfl(my_col, eA), cB = __shfl(my_col, eB);
            float wA = __shfl(my_w, eA), wB = __shfl(my_w, eB);
            uint2 hA = *(const uint2*)(h2f8 + (size_t)cA * 128 + k8 * 8);
            uint2 hB = *(const uint2*)(h2f8 + (size_t)cB * 128 + k8 * 8);
            v2f p;
            p = fp8x2f<false>(hA.x); acc[0] += wA * p.x; acc[1] += wA * p.y;
            p = fp8x2f<true>(hA.x);  acc[2] += wA * p.x; acc[3] += wA * p.y;
            p = fp8x2f<false>(hA.y); acc[4] += wA * p.x; acc[5] += wA * p.y;
            p = fp8x2f<true>(hA.y);  acc[6] += wA * p.x; acc[7] += wA * p.y;
            p = fp8x2f<false>(hB.x); acc[0] += wB * p.x; acc[1] += wB * p.y;
            p = fp8x2f<true>(hB.x);  acc[2] += wB * p.x; acc[3] += wB * p.y;
            p = fp8x2f<false>(hB.y); acc[4] += wB * p.x; acc[5] += wB * p.y;
            p = fp8x2f<true>(hB.y);  acc[6] += wB * p.x; acc[7] += wB * p.y;
        }
    }
#pragma unroll
    for (int off = 1; off < 64; off <<= 1) den += __shfl_xor(den, off);
#pragma unroll
    for (int i = 0; i < 8; ++i) {
        acc[i] += __shfl_xor(acc[i], 16);
        acc[i] += __shfl_xor(acc[i], 32);
    }
    if (lane < 16) {
        float invd = 1.f / (den * S2);
        const float4* bb = (const float4*)b2;
        float4 o0 = bb[k8 * 2], o1 = bb[k8 * 2 + 1];
        float4* dst = (float4*)(x2 + (size_t)node * 128 + k8 * 8);
        dst[0] = make_float4(acc[0] * invd + o0.x, acc[1] * invd + o0.y,
                             acc[2] * invd + o0.z, acc[3] * invd + o0.w);
        dst[1] = make_float4(acc[4] * invd + o1.x, acc[5] * invd + o1.y,
                             acc[6] * invd + o1.z, acc[7] * invd + o1.w);
    }
}

// ---- mean pool over sorted batch (run-length chunked atomics) ----
__global__ __launch_bounds__(128) void k_pool(const float* __restrict__ x2,
                                              const int* __restrict__ batch,
                                              float* __restrict__ pooled,
                                              float* __restrict__ cnt, int N) {
    int t = threadIdx.x;
    int nstart = blockIdx.x * 128;
    if (nstart >= N) return;
    int nend = nstart + 128;
    if (nend > N) nend = N;
    float acc = 0.f;
    int cur = batch[nstart];
    int count = 0;
    for (int n = nstart; n < nend; ++n) {
        int g = batch[n];
        if (g != cur) {
            atomicAdd(&pooled[(size_t)cur * 128 + t], acc);
            if (t == 0) atomicAdd(&cnt[cur], (float)count);
            acc = 0.f;
            count = 0;
            cur = g;
        }
        acc += x2[(size_t)n * 128 + t];
        ++count;
    }
    atomicAdd(&pooled[(size_t)cur * 128 + t], acc);
    if (t == 0) atomicAdd(&cnt[cur], (float)count);
}

// ---- FC + log_softmax: one wave per graph ----
__global__ __launch_bounds__(64) void k_fc(const float* __restrict__ pooled,
                                           const float* __restrict__ cnt,
                                           const float* __restrict__ fcw,
                                           const float* __restrict__ fcb,
                                           float* __restrict__ out, int G) {
    int g = blockIdx.x;
    int c = threadIdx.x;
    float2 p = ((const float2*)pooled)[(size_t)g * 64 + c];
    float inv = 1.f / fmaxf(cnt[g], 1.f);
    p.x *= inv; p.y *= inv;
    float l[10];
#pragma unroll
    for (int j = 0; j < 10; ++j)
        l[j] = p.x * fcw[(2 * c) * 10 + j] + p.y * fcw[(2 * c + 1) * 10 + j];
#pragma unroll
    for (int j = 0; j < 10; ++j)
        for (int off = 1; off < 64; off <<= 1) l[j] += __shfl_xor(l[j], off);
    if (c == 0) {
        float lj[10];
        float m = -1e30f;
#pragma unroll
        for (int j = 0; j < 10; ++j) {
            lj[j] = l[j] + fcb[j];
            m = fmaxf(m, lj[j]);
        }
        float s = 0.f;
#pragma unroll
        for (int j = 0; j < 10; ++j) s += expf(lj[j] - m);
        float ls = logf(s);
#pragma unroll
        for (int j = 0; j < 10; ++j) out[(size_t)g * 10 + j] = lj[j] - m - ls;
    }
}

extern "C" void kernel_launch(void* const* d_in, const int* in_sizes, int n_in,
                              void* d_out, int out_size, void* d_ws, size_t ws_size,
                              hipStream_t stream) {
    const float* x     = (const float*)d_in[0];
    const int*   ei    = (const int*)d_in[1];
    const int*   batch = (const int*)d_in[2];
    const float* W1    = (const float*)d_in[3];
    const float* as1   = (const float*)d_in[4];
    const float* ad1   = (const float*)d_in[5];
    const float* b1    = (const float*)d_in[6];
    const float* W2    = (const float*)d_in[7];
    const float* as2   = (const float*)d_in[8];
    const float* ad2   = (const float*)d_in[9];
    const float* b2    = (const float*)d_in[10];
    const float* fcw   = (const float*)d_in[11];
    const float* fcb   = (const float*)d_in[12];
    float* out = (float*)d_out;

    const int N = in_sizes[0] / 128;
    const int E = in_sizes[1] / 2;
    const int G = out_size / 10;
    const int* srcp = ei;
    const int* dstp = ei + E;

    // workspace (float units):
    //   [0,16N)     h1f8 (N*64 fp8)   -- dead after k_edge1
    //   [16N,80N)   x1pre (f32 N*64)  -- dead after k_gemm2
    //   [0,128N)    x2 (f32 N*128)    -- aliases dead h1f8/x1pre
    //   [128N,160N) h2f8 (N*128 fp8)
    //   [160N,168N) al1s  [168N,176N) al1d  [176N,177N) al2s  [177N,178N) al2d
    //   [178N,...)  pooled[G*128], cnt[G], then int region (ebuf, counts, btot, bbase, row_ptr, col)
    float* wf = (float*)d_ws;
    uchar* h1f8   = (uchar*)wf;
    float* x1pre  = wf + (size_t)N * 16;
    float* x2     = wf;
    uchar* h2f8   = (uchar*)(wf + (size_t)N * 128);
    float* al1s_  = wf + (size_t)N * 160;
    float* al1d_  = wf + (size_t)N * 168;
    float* al2s_  = wf + (size_t)N * 176;
    float* al2d_  = wf + (size_t)N * 177;
    float* pooled = wf + (size_t)N * 178;
    float* cnt    = pooled + (size_t)G * 128;

    const int NB = (N + 127) >> 7;      // 782 buckets (requires NB <= 1024, LDS arrays 784)
    const int C  = 1024;                // histogram/scatter blocks
    const int CH = (E + C - 1) / C;     // edges per block

    int* ib = (int*)(((uintptr_t)(cnt + G) + 15) & ~(uintptr_t)15);
    int2* ebuf   = (int2*)ib;                       // [E]
    int* counts  = ib + 2 * (size_t)E;              // [C*NB]
    int* btot    = counts + (size_t)C * NB;         // [NB]
    int* bbase   = btot + NB;                       // [NB+1]
    int* row_ptr = bbase + NB + 1;                  // [N+1]
    int* col     = row_ptr + N + 1;                 // [E+N]

    size_t zbytes = ((size_t)G * 128 + G) * sizeof(float);
    (void)hipMemsetAsync(pooled, 0, zbytes, stream);

    const int nb64 = (N + 63) / 64;
    const int nb4  = (N + 3) / 4;
    const int nbP  = (N + 127) / 128;

    k_hist<<<C, 256, 0, stream>>>(dstp, counts, E, CH, NB);
    k_gemm1<<<nb64, 256, 0, stream>>>(x, W1, as1, ad1, h1f8, al1s_, al1d_, N);
    k_bscan<<<NB, 256, 0, stream>>>(counts, btot, C, NB);
    k_bscan2<<<1, 1024, 0, stream>>>(btot, bbase, NB, E);
    k_bucket<<<C, 256, 0, stream>>>(srcp, dstp, counts, bbase, ebuf, E, CH, NB);
    k_csr<<<NB, 256, 0, stream>>>(bbase, ebuf, row_ptr, col, N, E);
    k_edge1<<<nb4, 256, 0, stream>>>(h1f8, al1s_, al1d_, row_ptr, col, x1pre, N);
    k_gemm2<<<nb64, 256, 0, stream>>>(x1pre, W2, b1, as2, ad2, h2f8, al2s_, al2d_, N);
    k_edge2<<<nb4, 256, 0, stream>>>(h2f8, al2s_, al2d_, row_ptr, col, b2, x2, N);
    k_pool<<<nbP, 128, 0, stream>>>(x2, batch, pooled, cnt, N);
    k_fc<<<G, 64, 0, stream>>>(pooled, cnt, fcw, fcb, out, G);
}